// Round 10
// baseline (188.039 us; speedup 1.0000x reference)
//
#include <hip/hip_runtime.h>
#include <stdint.h>
#include <stddef.h>

// Problem constants
#define BSZ 128
#define CIN 32
#define COUT 32
#define HN 4096
#define K7 7
#define NTOT (BSZ*CIN*HN)     // 16,777,216 elements
#define NBH  (BSZ*HN)         // 524,288 (b,h) pairs

typedef __attribute__((ext_vector_type(8))) short short8;
typedef __attribute__((ext_vector_type(4))) float f32x4;
typedef __attribute__((ext_vector_type(4))) unsigned int u32x4;
typedef __attribute__((ext_vector_type(2))) unsigned int u32x2;

// ws layout (bytes). NOTE: xt lives in the UPPER HALF OF d_out (d_out is 67MB
// f32; xt is 33.5MB bf16, dead before kbn overwrites d_out).
#define WS_OB   0            // bf16 out_pre[B][COUT][H]     : 33,554,432 B
#define WS_WT   33554432     // bf16 wt[o][kk][c]            : 14,336 B
#define WS_NBR  33568768     // int32 nbr_pack[H][8]         : 131,072 B
#define WS_INVD 33699840     // float invd[H]                : 16,384 B
#define WS_OSTP 33716224     // float ostatp[256][64]        : 65,536 B
#define WS_OST  33781760     // float ostat[64] = {sc[32], sh[32]} : 256 B

// LESSONS LEDGER:
// R3: no __threadfence() in wide kernels (L2-writeback per block: 3x).
// R4: __builtin_nontemporal_* NET NEGATIVE on every stream. Plain only.
// R6: halving gather *lines* (b-pair) = null. Not line-BW bound.
// R7: L2-warming = null; gathers were already 93% L2-resident.
// R8: LDS-serving taps lost to staging traffic + conflicts + 2B stores.
// R9: fully-DENSE gather (1KB coalesced, zero scatter) = null, even with
//     44% HBM service. All variants: ~14.3K segs/CU at ~7cyc/seg.
// => Surviving model: per-wave SERIALIZATION (unroll-1 loop = 4 serial
//    latency stalls/wave, ~11 resident waves -> MLP ~77 segs/CU).
//    R10 lever: hand depth-2 pipeline, all 14 gathers in flight at once.

__device__ __forceinline__ unsigned short f32_to_bf16(float f){
    union { float f; uint32_t u; } v; v.f = f;
    uint32_t u = v.u;
    return (unsigned short)((u + 0x7FFFu + ((u >> 16) & 1u)) >> 16);
}
__device__ __forceinline__ float bf16_to_f32(unsigned short h){
    union { uint32_t u; float f; } v; v.u = ((uint32_t)h) << 16;
    return v.f;
}

// ---------------------------------------------------------------------------
// ktrans: transpose x[B][C][H] f32 -> xt[B][H][C] bf16 (R1 layout).
// grid = 128 b * 16 h-tiles(256h) = 2048 blocks of 256.
// kinit fold: blocks 0..15 neighbor table + invd + zero ostatp; block 16
// packs weights.
__global__ void ktrans(const float* __restrict__ x,
                       unsigned short* __restrict__ xt,
                       const int* __restrict__ nbr,
                       const float* __restrict__ w,
                       int* __restrict__ nbr_pack,
                       float* __restrict__ invd,
                       unsigned short* __restrict__ wt,
                       float* __restrict__ ostatp){
    __shared__ float tile[32][260];       // rows 16B-aligned (260*4=1040)
    int b  = blockIdx.x >> 4;
    int h0 = (blockIdx.x & 15) << 8;
    int t  = threadIdx.x;
    #pragma unroll
    for (int l = 0; l < 8; l++){
        int linear = l*256 + t;
        int c  = linear >> 6;
        int h4 = linear & 63;
        f32x4 v = *(const f32x4*)(x + ((size_t)(b*CIN + c))*HN + h0 + h4*4);
        *(f32x4*)&tile[c][h4*4] = v;      // contiguous b128 stores: conflict-free
    }
    __syncthreads();
    int cg = (t & 3) * 8;
    int hw = t >> 2;                      // 0..63
    #pragma unroll
    for (int r = 0; r < 4; r++){
        int h = r*64 + hw;
        alignas(16) unsigned short tmp[8];
        #pragma unroll
        for (int j = 0; j < 8; j++) tmp[j] = f32_to_bf16(tile[cg + j][h]);
        *(u32x4*)(xt + ((size_t)(b*HN + h0 + h))*32 + cg) = *(const u32x4*)tmp;
    }
    // ---- folded kinit work (independent of above; no extra sync needed) ----
    if (blockIdx.x < 16){
        int h = blockIdx.x*256 + t;       // 0..4095
        #pragma unroll
        for (int j = 0; j < 4; j++) ostatp[h*4 + j] = 0.0f;   // 16384 floats
        int cnt = 0;
        int pk[8];
        #pragma unroll
        for (int j = 0; j < 6; j++){
            int iv = nbr[h*6 + j];
            if (iv >= HN) iv = HN - 1;    // safety clamp (never expected)
            if (iv >= 0) cnt++; else iv = -1;
            pk[j] = iv;
        }
        pk[6] = cnt; pk[7] = 0;
        #pragma unroll
        for (int j = 0; j < 8; j++) nbr_pack[h*8 + j] = pk[j];
        invd[h] = 1.0f / ((float)cnt + 1.0f + 1e-6f);
    } else if (blockIdx.x == 16){
        for (int i = t; i < COUT*K7*CIN; i += 256){
            int o  = i / (K7*CIN);
            int kk = (i / CIN) % K7;
            int c  = i % CIN;
            wt[i] = f32_to_bf16(w[(o*CIN + c)*K7 + kk]);
        }
    }
}

// ---------------------------------------------------------------------------
// kconv (R10): depth-2 hand pipeline. 4096 blocks x 256 (4 waves); block =
// (b, 128 h); wave = 32 h = 2 tiles of 16. blk&7 = XCD slot (16 b/XCD ->
// 4MB L2 working set, gathers ~93% L2-hit as in R1).
// Wave schedule: [4 idx loads] -> [all 14 gather loads issued back-to-back]
// -> MFMA tile0 (vmcnt leaves tile1's 7 loads in flight) -> epi0 ->
// MFMA tile1 -> epi1 -> coalesced stores. Two latency stalls per wave
// instead of four; 2x in-flight gather segments per wave.
__global__ __launch_bounds__(256) void kconv(
    const unsigned short* __restrict__ xt,
    const unsigned short* __restrict__ wt,
    const int* __restrict__ nbrp,
    const float* __restrict__ invd,
    unsigned short* __restrict__ ob,
    float* __restrict__ ostatp)
{
    // per-wave staging: [o][lh] stride 40 shorts (80B = 5*16B: all 8-short
    // pieces stay 16B-aligned; 20-bank row step).
    __shared__ unsigned short otile[4][32][40];   // 10,240 B

    int lane = threadIdx.x & 63;
    int wv   = threadIdx.x >> 6;
    int n    = lane & 15;
    int quad = lane >> 4;
    int xcd  = blockIdx.x & 7;
    int j    = blockIdx.x >> 3;           // 0..511
    int b    = xcd*16 + (j >> 5);         // 0..127
    int hbase= (j & 31)*128 + wv*32;      // wave: h in [hbase, hbase+32)

    const unsigned short* xb = xt + (size_t)b*HN*CIN;

    // --- neighbor tables + invd for BOTH tiles, issued first ---
    int h0 = hbase + n;
    int h1 = hbase + 16 + n;
    int4 na0 = *(const int4*)(nbrp + h0*8);
    int4 nb0 = *(const int4*)(nbrp + h0*8 + 4);
    int4 na1 = *(const int4*)(nbrp + h1*8);
    int4 nb1 = *(const int4*)(nbrp + h1*8 + 4);
    float idv0 = invd[h0];
    float idv1 = invd[h1];

    // A fragments (W): lane holds W[o=n+16mt][ik=kk*32 + quad*8 + jj]
    // (issued while the nbr-table loads are in flight)
    short8 af[2][K7];
    #pragma unroll
    for (int mt = 0; mt < 2; mt++){
        int o = n + 16*mt;
        #pragma unroll
        for (int kk = 0; kk < K7; kk++)
            af[mt][kk] = *(const short8*)(wt + (size_t)(o*K7 + kk)*CIN + quad*8);
    }

    const short8 zero8 = {0,0,0,0,0,0,0,0};

    // --- issue ALL 14 gather loads back-to-back ---
    short8 g0[K7], g1[K7];
    g0[0] = *(const short8*)(xb + (size_t)h0*CIN + quad*8);
    {
        int rows[6] = {na0.x, na0.y, na0.z, na0.w, nb0.x, nb0.y};
        #pragma unroll
        for (int kk = 0; kk < 6; kk++){
            int row = rows[kk];
            int rc  = row < 0 ? 0 : row;
            g0[kk+1] = *(const short8*)(xb + (size_t)rc*CIN + quad*8);
            if (row < 0) g0[kk+1] = zero8;
        }
    }
    g1[0] = *(const short8*)(xb + (size_t)h1*CIN + quad*8);
    {
        int rows[6] = {na1.x, na1.y, na1.z, na1.w, nb1.x, nb1.y};
        #pragma unroll
        for (int kk = 0; kk < 6; kk++){
            int row = rows[kk];
            int rc  = row < 0 ? 0 : row;
            g1[kk+1] = *(const short8*)(xb + (size_t)rc*CIN + quad*8);
            if (row < 0) g1[kk+1] = zero8;
        }
    }

    float sacc[8]  = {0,0,0,0,0,0,0,0};
    float sacc2[8] = {0,0,0,0,0,0,0,0};

    // --- tile 0: MFMA + epilogue (tile1's loads stay in flight) ---
    {
        f32x4 acc0 = {0.f,0.f,0.f,0.f};
        f32x4 acc1 = {0.f,0.f,0.f,0.f};
        #pragma unroll
        for (int kk = 0; kk < K7; kk++){
            acc0 = __builtin_amdgcn_mfma_f32_16x16x32_bf16(af[0][kk], g0[kk], acc0, 0, 0, 0);
            acc1 = __builtin_amdgcn_mfma_f32_16x16x32_bf16(af[1][kk], g0[kk], acc1, 0, 0, 0);
        }
        #pragma unroll
        for (int mt = 0; mt < 2; mt++){
            f32x4 a = mt ? acc1 : acc0;
            #pragma unroll
            for (int r = 0; r < 4; r++){
                int o = mt*16 + quad*4 + r;
                float v = a[r]*idv0;
                otile[wv][o][n] = f32_to_bf16(v);
                sacc[mt*4 + r]  += v;
                sacc2[mt*4 + r] += v*v;
            }
        }
    }
    // --- tile 1: MFMA + epilogue ---
    {
        f32x4 acc0 = {0.f,0.f,0.f,0.f};
        f32x4 acc1 = {0.f,0.f,0.f,0.f};
        #pragma unroll
        for (int kk = 0; kk < K7; kk++){
            acc0 = __builtin_amdgcn_mfma_f32_16x16x32_bf16(af[0][kk], g1[kk], acc0, 0, 0, 0);
            acc1 = __builtin_amdgcn_mfma_f32_16x16x32_bf16(af[1][kk], g1[kk], acc1, 0, 0, 0);
        }
        #pragma unroll
        for (int mt = 0; mt < 2; mt++){
            f32x4 a = mt ? acc1 : acc0;
            #pragma unroll
            for (int r = 0; r < 4; r++){
                int o = mt*16 + quad*4 + r;
                float v = a[r]*idv1;
                otile[wv][o][16 + n] = f32_to_bf16(v);
                sacc[mt*4 + r]  += v;
                sacc2[mt*4 + r] += v*v;
            }
        }
    }

    // wave-private tile -> coalesced global stores (64B dense per o-row).
    #pragma unroll
    for (int r = 0; r < 2; r++){
        int o     = lane >> 1;            // 0..31
        int piece = (lane & 1) + r*2;     // 4 pieces x 8 shorts = 32 h
        u32x4 vv = *(const u32x4*)&otile[wv][o][piece*8];
        *(u32x4*)(ob + ((size_t)(b*COUT + o))*HN + hbase + piece*8) = vv;
    }

    // reduce BN partials over the 16 n-lanes
    #pragma unroll
    for (int bit = 1; bit < 16; bit <<= 1){
        #pragma unroll
        for (int i = 0; i < 8; i++){
            sacc[i]  += __shfl_xor(sacc[i],  bit);
            sacc2[i] += __shfl_xor(sacc2[i], bit);
        }
    }
    if (n == 0){
        int slot = blockIdx.x & 255;
        #pragma unroll
        for (int mt = 0; mt < 2; mt++)
            #pragma unroll
            for (int r = 0; r < 4; r++){
                int o = mt*16 + quad*4 + r;
                atomicAdd(&ostatp[slot*64 + o],      sacc[mt*4 + r]);
                atomicAdd(&ostatp[slot*64 + 32 + o], sacc2[mt*4 + r]);
            }
    }
}

// ---------------------------------------------------------------------------
// kred: fold ostatp[256][64] -> ostat = {sc[32], sh[32]}. One block of 256.
__global__ void kred(const float* __restrict__ ostatp,
                     float* __restrict__ ostat,
                     const float* __restrict__ gamma,
                     const float* __restrict__ beta){
    __shared__ float part[4][64];
    int t = threadIdx.x;
    int a = t & 63;
    int g = t >> 6;
    float s = 0.0f;
    #pragma unroll
    for (int j = 0; j < 64; j++)
        s += ostatp[(g*64 + j)*64 + a];
    part[g][a] = s;
    __syncthreads();
    if (t < 64)
        part[0][t] = part[0][t] + part[1][t] + part[2][t] + part[3][t];
    __syncthreads();
    if (t < 32){
        float mean = part[0][t]      * (1.0f/(float)NBH);
        float var  = part[0][32 + t] * (1.0f/(float)NBH) - mean*mean;
        float sc = gamma[t] * rsqrtf(var + 1e-5f);
        ostat[t]      = sc;
        ostat[32 + t] = beta[t] - mean*sc;
    }
}

// ---------------------------------------------------------------------------
// kbn: read bf16 out_pre, apply precomputed scale/shift, write f32 d_out.
// Per-thread: one u32x2 (4 bf16) load -> one f32x4 store => every store
// instruction is a DENSE 1KB/wave line write. Plain accesses (R4: nt hurt).
__global__ void kbn(const unsigned short* __restrict__ ob,
                    float* __restrict__ out,
                    const float* __restrict__ ostat){
    __shared__ float sc[32], sh[32];
    int t = threadIdx.x;
    if (t < 32){ sc[t] = ostat[t]; sh[t] = ostat[32 + t]; }
    __syncthreads();
    int gid = blockIdx.x*256 + t;
    const u32x2* ob2 = (const u32x2*)ob;
    f32x4* out4 = (f32x4*)out;
    #pragma unroll
    for (int k = 0; k < 8; k++){
        int i = gid + k*(2048*256);               // i < NTOT/4 = 4,194,304
        int o = (i >> 10) & 31;                   // (i*4 / 4096) % 32
        u32x2 raw = *(ob2 + i);
        const unsigned short* p = (const unsigned short*)&raw;
        float s = sc[o], bsh = sh[o];
        f32x4 r;
        r.x = bf16_to_f32(p[0])*s + bsh;
        r.y = bf16_to_f32(p[1])*s + bsh;
        r.z = bf16_to_f32(p[2])*s + bsh;
        r.w = bf16_to_f32(p[3])*s + bsh;
        *(out4 + i) = r;
    }
}

// ---------------------------------------------------------------------------
extern "C" void kernel_launch(void* const* d_in, const int* in_sizes, int n_in,
                              void* d_out, int out_size, void* d_ws, size_t ws_size,
                              hipStream_t stream) {
    const float* x      = (const float*)d_in[0];
    const float* weight = (const float*)d_in[1];
    // d_in[2] = bias  — exactly cancelled by BatchNorm mean subtraction
    const float* gamma  = (const float*)d_in[3];
    const float* beta   = (const float*)d_in[4];
    const int*   nbr    = (const int*)d_in[5];   // int64 in reference -> int32 from harness
    // d_in[6] = groups (==1), ignored

    char* ws = (char*)d_ws;
    unsigned short* ob    = (unsigned short*)(ws + WS_OB);
    unsigned short* wt    = (unsigned short*)(ws + WS_WT);
    int*            nbrp  = (int*)(ws + WS_NBR);
    float*          invd  = (float*)(ws + WS_INVD);
    float*          ostatp= (float*)(ws + WS_OSTP);
    float*          ostat = (float*)(ws + WS_OST);
    float*          out   = (float*)d_out;
    // xt (bf16, 33.5MB) lives in the upper half of d_out; dead before kbn
    // overwrites d_out (stream-ordered).
    unsigned short* xt    = (unsigned short*)d_out + 16777216;

    ktrans<<<2048, 256, 0, stream>>>(x, xt, nbr, weight, nbrp, invd, wt, ostatp);
    kconv <<<4096, 256, 0, stream>>>(xt, wt, nbrp, invd, ob, ostatp);
    kred  <<<1,    256, 0, stream>>>(ostatp, ostat, gamma, beta);
    kbn   <<<2048, 256, 0, stream>>>(ob, out, ostat);
}